// Round 8
// baseline (275.500 us; speedup 1.0000x reference)
//
#include <hip/hip_runtime.h>
#include <math.h>

#define BS 2
#define NQ 21760
#define V_LEN 21760
#define EMBED 256
#define NH 8
#define NL 4
#define NP 4
#define HD 32

typedef __bf16 bf16;
typedef __bf16 bf16x8 __attribute__((ext_vector_type(8)));
typedef __bf16 bf16x4 __attribute__((ext_vector_type(4)));
typedef float f32x4 __attribute__((ext_vector_type(4)));
typedef float f32x2 __attribute__((ext_vector_type(2)));
typedef unsigned int u32;

// async global->LDS, 16B per lane. LDS dest must be lane-linear (base + lane*16).
#define GLOAD_LDS16(gp, lp_) \
    __builtin_amdgcn_global_load_lds( \
        (const __attribute__((address_space(1))) unsigned int*)(gp), \
        (__attribute__((address_space(3))) unsigned int*)(lp_), 16, 0, 0)

// ---------------- fused prologue: LDS-tiled transpose+cast of all weights + bias concat
__global__ __launch_bounds__(256) void cast_all(
    const float* __restrict__ W_v, const float* __restrict__ W_off,
    const float* __restrict__ W_attn, const float* __restrict__ W_out,
    const float* __restrict__ b_off, const float* __restrict__ b_attn,
    bf16* __restrict__ WTv, bf16* __restrict__ WToa, bf16* __restrict__ WTu,
    float* __restrict__ bcat)
{
    const int bid = blockIdx.x;
    const int tid = threadIdx.x;
    if (bid == 56) {
        if (tid < 384) bcat[tid] = (tid < 256) ? b_off[tid] : b_attn[tid - 256];
        return;
    }
    const float* W; bf16* WT; int N, tile;
    if (bid < 16)      { W = W_v;    WT = WTv;           N = 256; tile = bid; }
    else if (bid < 32) { W = W_off;  WT = WToa;          N = 256; tile = bid - 16; }
    else if (bid < 40) { W = W_attn; WT = WToa + 65536;  N = 128; tile = bid - 32; }
    else               { W = W_out;  WT = WTu;           N = 256; tile = bid - 40; }
    const int ntn = N >> 6;
    const int k0 = (tile / ntn) * 64, n0 = (tile % ntn) * 64;

    __shared__ float lds[64][65];
    const int c = tid & 63, r4 = tid >> 6;
    #pragma unroll
    for (int p = 0; p < 16; p++) {
        int rr = r4 + p * 4;
        lds[rr][c] = W[(size_t)(k0 + rr) * N + n0 + c];   // coalesced 256B rows
    }
    __syncthreads();
    #pragma unroll
    for (int p = 0; p < 16; p++) {
        int i = r4 + p * 4;                                // n index
        WT[(size_t)(n0 + i) * 256 + k0 + c] = (bf16)lds[c][i];  // coalesced 128B rows
    }
}

// ---------------- bf16 MFMA GEMM: C[M,N] = A[M,K=256] @ WT^T + bias
// A staged via global_load_lds double-buffer; B (weights, L2-hot) read DIRECT
// to registers with compile-time offsets (no LDS, no per-step addr VALU).
// loadB(t) issued BEFORE stageA(t+1) so backend's auto-wait for bfr is
// vmcnt(4) (A(t+1) stays in flight); manual vmcnt(NA+4) guards A(t) tile.
// OUT_MODE: 0 = fp32 linear, 1 = bf16 linear, 2 = bf16 per-head vproj layout
template<bool A_F32, int OUT_MODE>
__global__ __launch_bounds__(256) void gemm_mfma(
    const void* __restrict__ Av, const bf16* __restrict__ WT,
    const float* __restrict__ bias, void* __restrict__ Cv,
    int N, int ntn)
{
    const int nmt = gridDim.x / ntn;
    const int bmt = blockIdx.x % nmt;     // row-fastest
    const int bnt = blockIdx.x / nmt;
    const int bm = bmt * 128, bn = bnt * 128;

    __shared__ __align__(16) unsigned char AsRaw[2][A_F32 ? 128 * 32 * 4
                                                         : 128 * 32 * 2];

    const int tid = threadIdx.x;
    const int lane = tid & 63, wv = tid >> 6;
    const int wr = wv >> 1, wc = wv & 1;
    const int quad = lane >> 4, l16 = lane & 15;

    f32x4 acc[4][4];
    #pragma unroll
    for (int i = 0; i < 4; i++)
        #pragma unroll
        for (int j = 0; j < 4; j++)
            acc[i][j] = (f32x4){0.f, 0.f, 0.f, 0.f};

    const int b_row = tid >> 2, b_chunk = tid & 3;   // bf16 staging
    const int a_row8 = tid >> 3, a_phys = tid & 7;   // f32 staging
    constexpr int NA = A_F32 ? 4 : 2;                // A gload_lds per thread per step

    // B fragment base pointers (lane-resident, loop-invariant)
    const bf16* bB[4];
    #pragma unroll
    for (int ni = 0; ni < 4; ni++)
        bB[ni] = WT + (size_t)(bn + wc * 64 + ni * 16 + l16) * 256 + quad * 8;

    auto stage = [&](int buf, int k0) {
        if constexpr (A_F32) {
            const float* A = (const float*)Av;
            #pragma unroll
            for (int p = 0; p < 4; p++) {
                int row = a_row8 + p * 32;
                int csrc = a_phys ^ (row & 7);       // inverse-swizzled source chunk
                GLOAD_LDS16(&A[(size_t)(bm + row) * 256 + k0 + csrc * 4],
                            &AsRaw[buf][p * 4096 + tid * 16]);
            }
        } else {
            const bf16* A = (const bf16*)Av;
            #pragma unroll
            for (int p = 0; p < 2; p++) {
                int row = b_row + p * 64;
                GLOAD_LDS16(&A[(size_t)(bm + row) * 256 + k0 + b_chunk * 8],
                            &AsRaw[buf][p * 4096 + tid * 16]);
            }
        }
    };

    stage(0, 0);
    int cur = 0;
    #pragma unroll
    for (int t = 0; t < 8; t++) {
        __builtin_amdgcn_s_barrier();               // prev step's LDS reads all done
        bf16x8 bfr[4];
        #pragma unroll
        for (int ni = 0; ni < 4; ni++)              // B direct: imm offset t*64B
            bfr[ni] = *(const bf16x8*)(bB[ni] + t * 32);
        if (t < 7) {
            stage(cur ^ 1, (t + 1) * 32);           // prefetch next A tile
            asm volatile("s_waitcnt vmcnt(%0)" :: "n"(NA + 4) : "memory");  // A(t) landed
        } else {
            asm volatile("s_waitcnt vmcnt(4)" ::: "memory");                // A(7) landed
        }
        __builtin_amdgcn_s_barrier();               // all waves' A(t) loads landed

        bf16x8 af[4];
        if constexpr (A_F32) {
            const float* Asf = (const float*)&AsRaw[cur][0];  // [128][32] f32, chunk-swizzled
            #pragma unroll
            for (int mi = 0; mi < 4; mi++) {
                int r = wr * 64 + mi * 16 + l16;
                int g = r & 7;
                f32x4 u0 = *(const f32x4*)&Asf[r * 32 + ((2 * quad) ^ g) * 4];
                f32x4 u1 = *(const f32x4*)&Asf[r * 32 + ((2 * quad + 1) ^ g) * 4];
                bf16x8 hh;
                hh[0] = (bf16)u0[0]; hh[1] = (bf16)u0[1]; hh[2] = (bf16)u0[2]; hh[3] = (bf16)u0[3];
                hh[4] = (bf16)u1[0]; hh[5] = (bf16)u1[1]; hh[6] = (bf16)u1[2]; hh[7] = (bf16)u1[3];
                af[mi] = hh;
            }
        } else {
            const bf16* Asb = (const bf16*)&AsRaw[cur][0];    // [128][32] bf16, linear
            #pragma unroll
            for (int mi = 0; mi < 4; mi++) {
                int r = wr * 64 + mi * 16 + l16;
                af[mi] = *(const bf16x8*)&Asb[r * 32 + quad * 8];
            }
        }
        #pragma unroll
        for (int mi = 0; mi < 4; mi++)
            #pragma unroll
            for (int ni = 0; ni < 4; ni++)
                acc[mi][ni] = __builtin_amdgcn_mfma_f32_16x16x32_bf16(
                    af[mi], bfr[ni], acc[mi][ni], 0, 0, 0);
        cur ^= 1;
    }

    // epilogue
    #pragma unroll
    for (int mi = 0; mi < 4; mi++) {
        #pragma unroll
        for (int ni = 0; ni < 4; ni++) {
            const int col = bn + wc * 64 + ni * 16 + l16;
            const int row0 = bm + wr * 64 + mi * 16 + quad * 4;
            const float bc = bias[col];
            #pragma unroll
            for (int r = 0; r < 4; r++) {
                float v = acc[mi][ni][r] + bc;
                if constexpr (OUT_MODE == 0) {
                    ((float*)Cv)[(size_t)(row0 + r) * N + col] = v;
                } else if constexpr (OUT_MODE == 1) {
                    ((bf16*)Cv)[(size_t)(row0 + r) * N + col] = (bf16)v;
                } else {
                    int rv = row0 + r;
                    int bb = (rv >= V_LEN) ? 1 : 0;
                    int vv = rv - bb * V_LEN;
                    ((bf16*)Cv)[((size_t)(bb * NH + (col >> 5)) * V_LEN + vv) * 32
                                + (col & 31)] = (bf16)v;
                }
            }
        }
    }
}

// 8-channel bf16->f32 unpack + weighted accumulate into 4 packed f32x2
__device__ inline void acc8(const uint4& rr, float ww,
                            f32x2& a01, f32x2& a23, f32x2& a45, f32x2& a67)
{
    f32x2 v;
    v[0] = __uint_as_float(rr.x << 16); v[1] = __uint_as_float(rr.x & 0xFFFF0000u); a01 += v * ww;
    v[0] = __uint_as_float(rr.y << 16); v[1] = __uint_as_float(rr.y & 0xFFFF0000u); a23 += v * ww;
    v[0] = __uint_as_float(rr.z << 16); v[1] = __uint_as_float(rr.z & 0xFFFF0000u); a45 += v * ww;
    v[0] = __uint_as_float(rr.w << 16); v[1] = __uint_as_float(rr.w & 0xFFFF0000u); a67 += v * ww;
}

// ---------------- Deformable sampling, per-(b,h) L2-resident slabs.
// Block = 256 thr = 4 waves; block handles 32 queries x ONE (b,h).
// Wave = 8 queries x 8 lanes. Lane (qq=t>>3, j=t&7): owns x-slot j>>2,
// channel group j&3 (8 ch); loads BOTH y-rows per sample (2x16B of the fully
// used 128B pair-lines). Softmax/precompute: lane (qq, e=t&7) handles logits
// e, e+8. s_idx stores BYTE offsets (32-bit saddr+voffset addressing);
// s_w stored [y0x0,y1x0,y0x1,y1x1] so gather reads one ds_read_b64, no selects.
// 17-entry padding -> gather-side LDS reads provably conflict-free.
__global__ __launch_bounds__(256) void deform_head(
    const bf16* __restrict__ vproj, const float* __restrict__ offaw,
    const float* __restrict__ refp, bf16* __restrict__ sampled)
{
    const int gid = blockIdx.x;
    const int idx8 = gid & 7;                 // -> XCD (round-robin heuristic)
    const int mid = gid >> 3;
    const int qg = mid % (NQ / 32);
    const int hsel = mid / (NQ / 32);         // 0 or 1 (grid-half)
    const int h = (idx8 >> 1) + (hsel << 2);
    const int b = idx8 & 1;

    const int wv = threadIdx.x >> 6;
    const int t = threadIdx.x & 63;
    const int qq = t >> 3, e = t & 7;
    const int wq = wv * 8 + qq;               // 0..31
    const int q = qg * 32 + wq;
    const int bq = b * NQ + q;

    __shared__ int   s_idx[32][17];           // byte offset of pair row
    __shared__ __align__(16) float s_w[32][17][4];  // [y0x0, y1x0, y0x1, y1x1]

    const float* row = offaw + (size_t)bq * 384;

    // ---- softmax over 16 logits: 8 lanes x 2, butterflies strides 1,2,4
    float l0 = row[256 + h * 16 + e];
    float l1 = row[256 + h * 16 + e + 8];
    float m = fmaxf(l0, l1);
    m = fmaxf(m, __shfl_xor(m, 1));
    m = fmaxf(m, __shfl_xor(m, 2));
    m = fmaxf(m, __shfl_xor(m, 4));
    float e0 = __expf(l0 - m), e1 = __expf(l1 - m);
    float ssum = e0 + e1;
    ssum += __shfl_xor(ssum, 1);
    ssum += __shfl_xor(ssum, 2);
    ssum += __shfl_xor(ssum, 4);
    float rs = 1.0f / ssum;
    float awv[2] = {e0 * rs, e1 * rs};

    // ---- precompute 2 samples per lane (lp = e, e+8), border-exact slot weights
    #pragma unroll
    for (int sI = 0; sI < 2; sI++) {
        int lp = e + sI * 8;
        int l = lp >> 2;
        int Wl = 128 >> l, Hl = Wl;
        int st = (l == 0) ? 0 : (l == 1) ? 16384 : (l == 2) ? 20480 : 21504;
        float2 rp = *(const float2*)&refp[((size_t)bq * 4 + l) * 2];
        float2 oxy = *(const float2*)&row[h * 32 + lp * 2];
        float fW = (float)Wl, fH = (float)Hl;
        float x = (rp.x + oxy.x / fW) * fW - 0.5f;
        float y = (rp.y + oxy.y / fH) * fH - 0.5f;
        float xf = floorf(x), yf = floorf(y);
        int x0 = (int)xf, y0 = (int)yf;
        float wx1 = x - xf, wx0 = 1.f - wx1;
        float wy1 = y - yf, wy0 = 1.f - wy1;
        float aw = awv[sI];
        float wx0p = ((x0 >= 0) && (x0 < Wl)) ? wx0 : 0.f;
        float wx1p = ((x0 + 1 >= 0) && (x0 + 1 < Wl)) ? wx1 : 0.f;
        float wy0p = ((y0 >= 0) && (y0 < Hl)) ? wy0 : 0.f;
        float wy1p = ((y0 + 1 >= 0) && (y0 + 1 < Hl)) ? wy1 : 0.f;
        int px = min(max(x0, 0), Wl - 2), py = min(max(y0, 0), Hl - 2);
        int cx0 = min(max(x0, 0), Wl - 1), cx1 = min(max(x0 + 1, 0), Wl - 1);
        int cy0 = min(max(y0, 0), Hl - 1), cy1 = min(max(y0 + 1, 0), Hl - 1);
        float sx0 = ((cx0 == px) ? wx0p : 0.f) + ((cx1 == px) ? wx1p : 0.f);
        float sx1 = ((cx0 == px + 1) ? wx0p : 0.f) + ((cx1 == px + 1) ? wx1p : 0.f);
        float sy0 = ((cy0 == py) ? wy0p : 0.f) + ((cy1 == py) ? wy1p : 0.f);
        float sy1 = ((cy0 == py + 1) ? wy0p : 0.f) + ((cy1 == py + 1) ? wy1p : 0.f);
        s_idx[wq][lp] = (st + py * Wl + px) * 64;   // byte offset ( *32ch *2B )
        s_w[wq][lp][0] = sy0 * sx0 * aw;            // y0, x0
        s_w[wq][lp][1] = sy1 * sx0 * aw;            // y1, x0
        s_w[wq][lp][2] = sy0 * sx1 * aw;            // y0, x1
        s_w[wq][lp][3] = sy1 * sx1 * aw;            // y1, x1
    }
    // wave-local LDS RAW (each wave reads only its own 8 wq rows) -> lgkmcnt only

    // ---- gather: lane (qq, j): xslot = j>>2, chgrp = j&3
    const int j = t & 7;
    const int xslot = j >> 2, chgrp = j & 3;
    const char* vb = (const char*)vproj + (size_t)(b * NH + h) * V_LEN * 64;
    const int voffbase = j * 16;   // xslot*64 + chgrp*16 within the 128B pair

    f32x2 a01 = {0.f, 0.f}, a23 = {0.f, 0.f}, a45 = {0.f, 0.f}, a67 = {0.f, 0.f};
    #pragma unroll
    for (int i = 0; i < 16; i++) {
        const int Wl = 128 >> (i >> 2);           // compile-time per unrolled iter
        int off = s_idx[wq][i] + voffbase;
        f32x2 wp = *(const f32x2*)&s_w[wq][i][xslot * 2];
        uint4 r0 = *(const uint4*)(vb + off);             // row py
        uint4 r1 = *(const uint4*)(vb + off + Wl * 64);   // row py+1
        acc8(r0, wp[0], a01, a23, a45, a67);
        acc8(r1, wp[1], a01, a23, a45, a67);
    }

    // combine x-slots (lanes j and j^4 hold same channels)
    float sarr[8] = {a01[0], a01[1], a23[0], a23[1], a45[0], a45[1], a67[0], a67[1]};
    #pragma unroll
    for (int i = 0; i < 8; i++) sarr[i] += __shfl_xor(sarr[i], 4);

    if ((t & 4) == 0) {                           // one lane per (query, chgrp)
        bf16x8 o;
        #pragma unroll
        for (int i = 0; i < 8; i++) o[i] = (bf16)sarr[i];
        *(bf16x8*)&sampled[(size_t)bq * 256 + h * 32 + chgrp * 8] = o;
    }
}

extern "C" void kernel_launch(void* const* d_in, const int* in_sizes, int n_in,
                              void* d_out, int out_size, void* d_ws, size_t ws_size,
                              hipStream_t stream)
{
    const float* query  = (const float*)d_in[0];
    const float* refp   = (const float*)d_in[1];
    const float* value  = (const float*)d_in[2];
    const float* W_off  = (const float*)d_in[3];
    const float* b_off  = (const float*)d_in[4];
    const float* W_attn = (const float*)d_in[5];
    const float* b_attn = (const float*)d_in[6];
    const float* W_v    = (const float*)d_in[7];
    const float* b_v    = (const float*)d_in[8];
    const float* W_out  = (const float*)d_in[9];
    const float* b_out  = (const float*)d_in[10];
    float* out = (float*)d_out;

    const int M = BS * NQ;  // 43520

    char* ws = (char*)d_ws;
    bf16*  WTv   = (bf16*)ws;                      ws += 256 * 256 * 2;
    bf16*  WToa  = (bf16*)ws;                      ws += 384 * 256 * 2;
    bf16*  WTu   = (bf16*)ws;                      ws += 256 * 256 * 2;
    float* bcat  = (float*)ws;                     ws += 384 * 4;
    bf16*  vproj = (bf16*)ws;                      ws += (size_t)M * 256 * 2;   // per-head layout
    float* offaw = (float*)ws;                     ws += (size_t)M * 384 * 4;
    bf16*  samp  = (bf16*)ws;                      ws += (size_t)M * 256 * 2;

    cast_all<<<57, 256, 0, stream>>>(W_v, W_off, W_attn, W_out, b_off, b_attn,
                                     WTv, WToa, WTu, bcat);

    // vproj = bf16(value @ W_v + b_v), per-head layout [b][h][v][32]
    gemm_mfma<true, 2><<<(M / 128) * 2, 256, 0, stream>>>(value, WTv, b_v, vproj, 256, 2);
    // offaw = query @ [W_off | W_attn] + [b_off | b_attn]   (fp32 out)
    gemm_mfma<true, 0><<<(M / 128) * 3, 256, 0, stream>>>(query, WToa, bcat, offaw, 384, 3);
    // softmax + deformable sampling -> bf16, per-(b,h) XCD-resident blocks
    deform_head<<<2 * NH * (NQ / 32), 256, 0, stream>>>(vproj, offaw, refp, samp);
    // out = sampled @ W_out + b_out  (fp32 out)
    gemm_mfma<false, 0><<<(M / 128) * 2, 256, 0, stream>>>(samp, WTu, b_out, out, 256, 2);
}

// Round 9
// 268.792 us; speedup vs baseline: 1.0250x; 1.0250x over previous
//
#include <hip/hip_runtime.h>
#include <math.h>

#define BS 2
#define NQ 21760
#define V_LEN 21760
#define EMBED 256
#define NH 8
#define NL 4
#define NP 4
#define HD 32

typedef __bf16 bf16;
typedef __bf16 bf16x8 __attribute__((ext_vector_type(8)));
typedef __bf16 bf16x4 __attribute__((ext_vector_type(4)));
typedef float f32x4 __attribute__((ext_vector_type(4)));
typedef float f32x2 __attribute__((ext_vector_type(2)));
typedef unsigned int u32;

// async global->LDS, 16B per lane. LDS dest must be lane-linear (base + lane*16).
#define GLOAD_LDS16(gp, lp_) \
    __builtin_amdgcn_global_load_lds( \
        (const __attribute__((address_space(1))) unsigned int*)(gp), \
        (__attribute__((address_space(3))) unsigned int*)(lp_), 16, 0, 0)

// ---------------- fused prologue: LDS-tiled transpose+cast of all weights + bias concat
__global__ __launch_bounds__(256) void cast_all(
    const float* __restrict__ W_v, const float* __restrict__ W_off,
    const float* __restrict__ W_attn, const float* __restrict__ W_out,
    const float* __restrict__ b_off, const float* __restrict__ b_attn,
    bf16* __restrict__ WTv, bf16* __restrict__ WToa, bf16* __restrict__ WTu,
    float* __restrict__ bcat)
{
    const int bid = blockIdx.x;
    const int tid = threadIdx.x;
    if (bid == 56) {
        if (tid < 384) bcat[tid] = (tid < 256) ? b_off[tid] : b_attn[tid - 256];
        return;
    }
    const float* W; bf16* WT; int N, tile;
    if (bid < 16)      { W = W_v;    WT = WTv;           N = 256; tile = bid; }
    else if (bid < 32) { W = W_off;  WT = WToa;          N = 256; tile = bid - 16; }
    else if (bid < 40) { W = W_attn; WT = WToa + 65536;  N = 128; tile = bid - 32; }
    else               { W = W_out;  WT = WTu;           N = 256; tile = bid - 40; }
    const int ntn = N >> 6;
    const int k0 = (tile / ntn) * 64, n0 = (tile % ntn) * 64;

    __shared__ float lds[64][65];
    const int c = tid & 63, r4 = tid >> 6;
    #pragma unroll
    for (int p = 0; p < 16; p++) {
        int rr = r4 + p * 4;
        lds[rr][c] = W[(size_t)(k0 + rr) * N + n0 + c];   // coalesced 256B rows
    }
    __syncthreads();
    #pragma unroll
    for (int p = 0; p < 16; p++) {
        int i = r4 + p * 4;                                // n index
        WT[(size_t)(n0 + i) * 256 + k0 + c] = (bf16)lds[c][i];  // coalesced 128B rows
    }
}

// ---------------- bf16 MFMA GEMM: C[M,N] = A[M,K] @ WT^T + bias
// Tile 128x128, BK=32, 2-phase double-buffered global_load_lds pipeline.
// (Round-6 form — best measured; B-direct variant regressed, reverted.)
// OUT_MODE: 0 = fp32 linear, 1 = bf16 linear, 2 = bf16 per-head vproj layout
template<bool A_F32, int OUT_MODE>
__global__ __launch_bounds__(256) void gemm_mfma(
    const void* __restrict__ Av, const bf16* __restrict__ WT,
    const float* __restrict__ bias, void* __restrict__ Cv,
    int N, int K, int ntn)
{
    const int nmt = gridDim.x / ntn;
    const int bmt = blockIdx.x % nmt;     // row-fastest
    const int bnt = blockIdx.x / nmt;
    const int bm = bmt * 128, bn = bnt * 128;

    __shared__ __align__(16) bf16 Bs[2][128 * 32];                       // 2x8 KB
    __shared__ __align__(16) unsigned char AsRaw[2][A_F32 ? 128 * 32 * 4
                                                         : 128 * 32 * 2];

    const int tid = threadIdx.x;
    const int lane = tid & 63, wv = tid >> 6;
    const int wr = wv >> 1, wc = wv & 1;
    const int quad = lane >> 4, l16 = lane & 15;

    f32x4 acc[4][4];
    #pragma unroll
    for (int i = 0; i < 4; i++)
        #pragma unroll
        for (int j = 0; j < 4; j++)
            acc[i][j] = (f32x4){0.f, 0.f, 0.f, 0.f};

    const int b_row = tid >> 2, b_chunk = tid & 3;   // bf16 staging: byte = p*4096 + tid*16
    const int a_row8 = tid >> 3, a_phys = tid & 7;   // f32 staging:  byte = p*4096 + tid*16
    constexpr int NB = A_F32 ? 6 : 4;                // global_load_lds per thread per step

    auto stage = [&](int buf, int k0) {
        if constexpr (A_F32) {
            const float* A = (const float*)Av;
            #pragma unroll
            for (int p = 0; p < 4; p++) {
                int row = a_row8 + p * 32;
                int csrc = a_phys ^ (row & 7);       // inverse-swizzled source chunk
                GLOAD_LDS16(&A[(size_t)(bm + row) * K + k0 + csrc * 4],
                            &AsRaw[buf][p * 4096 + tid * 16]);
            }
        } else {
            const bf16* A = (const bf16*)Av;
            #pragma unroll
            for (int p = 0; p < 2; p++) {
                int row = b_row + p * 64;
                GLOAD_LDS16(&A[(size_t)(bm + row) * K + k0 + b_chunk * 8],
                            &AsRaw[buf][p * 4096 + tid * 16]);
            }
        }
        #pragma unroll
        for (int p = 0; p < 2; p++) {
            int row = b_row + p * 64;
            GLOAD_LDS16(&WT[(size_t)(bn + row) * K + k0 + b_chunk * 8],
                        (unsigned char*)&Bs[buf][0] + p * 4096 + tid * 16);
        }
    };

    const int nt = K >> 5;   // 8
    stage(0, 0);
    int cur = 0;
    for (int t = 0; t < nt; t++) {
        __builtin_amdgcn_s_barrier();               // prev step's LDS reads all done
        if (t + 1 < nt) {
            stage(cur ^ 1, (t + 1) << 5);           // prefetch next tile (stays in flight)
            asm volatile("s_waitcnt vmcnt(%0)" :: "n"(NB) : "memory");  // cur tile landed
        } else {
            asm volatile("s_waitcnt vmcnt(0)" ::: "memory");
        }
        __builtin_amdgcn_s_barrier();               // all waves' cur-tile loads landed

        bf16x8 af[4], bfr[4];
        if constexpr (A_F32) {
            const float* Asf = (const float*)&AsRaw[cur][0];  // [128][32] f32, chunk-swizzled
            #pragma unroll
            for (int mi = 0; mi < 4; mi++) {
                int r = wr * 64 + mi * 16 + l16;
                int g = r & 7;
                f32x4 u0 = *(const f32x4*)&Asf[r * 32 + ((2 * quad) ^ g) * 4];
                f32x4 u1 = *(const f32x4*)&Asf[r * 32 + ((2 * quad + 1) ^ g) * 4];
                bf16x8 hh;
                hh[0] = (bf16)u0[0]; hh[1] = (bf16)u0[1]; hh[2] = (bf16)u0[2]; hh[3] = (bf16)u0[3];
                hh[4] = (bf16)u1[0]; hh[5] = (bf16)u1[1]; hh[6] = (bf16)u1[2]; hh[7] = (bf16)u1[3];
                af[mi] = hh;
            }
        } else {
            const bf16* Asb = (const bf16*)&AsRaw[cur][0];    // [128][32] bf16, linear
            #pragma unroll
            for (int mi = 0; mi < 4; mi++) {
                int r = wr * 64 + mi * 16 + l16;
                af[mi] = *(const bf16x8*)&Asb[r * 32 + quad * 8];
            }
        }
        #pragma unroll
        for (int ni = 0; ni < 4; ni++) {
            int r = wc * 64 + ni * 16 + l16;
            bfr[ni] = *(const bf16x8*)&Bs[cur][r * 32 + quad * 8];
        }
        #pragma unroll
        for (int mi = 0; mi < 4; mi++)
            #pragma unroll
            for (int ni = 0; ni < 4; ni++)
                acc[mi][ni] = __builtin_amdgcn_mfma_f32_16x16x32_bf16(
                    af[mi], bfr[ni], acc[mi][ni], 0, 0, 0);
        cur ^= 1;
    }

    // epilogue
    #pragma unroll
    for (int mi = 0; mi < 4; mi++) {
        #pragma unroll
        for (int ni = 0; ni < 4; ni++) {
            const int col = bn + wc * 64 + ni * 16 + l16;
            const int row0 = bm + wr * 64 + mi * 16 + quad * 4;
            const float bc = bias[col];
            #pragma unroll
            for (int r = 0; r < 4; r++) {
                float v = acc[mi][ni][r] + bc;
                if constexpr (OUT_MODE == 0) {
                    ((float*)Cv)[(size_t)(row0 + r) * N + col] = v;
                } else if constexpr (OUT_MODE == 1) {
                    ((bf16*)Cv)[(size_t)(row0 + r) * N + col] = (bf16)v;
                } else {
                    int rv = row0 + r;
                    int bb = (rv >= V_LEN) ? 1 : 0;
                    int vv = rv - bb * V_LEN;
                    ((bf16*)Cv)[((size_t)(bb * NH + (col >> 5)) * V_LEN + vv) * 32
                                + (col & 31)] = (bf16)v;
                }
            }
        }
    }
}

// 8-channel bf16->f32 unpack + weighted accumulate into 4 packed f32x2
__device__ inline void acc8(const uint4& rr, float ww,
                            f32x2& a01, f32x2& a23, f32x2& a45, f32x2& a67)
{
    f32x2 v;
    v[0] = __uint_as_float(rr.x << 16); v[1] = __uint_as_float(rr.x & 0xFFFF0000u); a01 += v * ww;
    v[0] = __uint_as_float(rr.y << 16); v[1] = __uint_as_float(rr.y & 0xFFFF0000u); a23 += v * ww;
    v[0] = __uint_as_float(rr.z << 16); v[1] = __uint_as_float(rr.z & 0xFFFF0000u); a45 += v * ww;
    v[0] = __uint_as_float(rr.w << 16); v[1] = __uint_as_float(rr.w & 0xFFFF0000u); a67 += v * ww;
}

// load group G (4 samples, 2 rows each) into 8 uint4 regs
template<int G>
__device__ inline void load_group(const char* vb, const int* offv, uint4* r)
{
    #pragma unroll
    for (int k = 0; k < 4; k++) {
        const int i = G * 4 + k;
        const int Wl = 128 >> (i >> 2);           // compile-time
        r[k * 2 + 0] = *(const uint4*)(vb + offv[i]);
        r[k * 2 + 1] = *(const uint4*)(vb + offv[i] + Wl * 64);
    }
}

// ---------------- Deformable sampling, per-(b,h) L2-resident slabs.
// Block = 256 thr = 4 waves; block handles 32 queries x ONE (b,h).
// Wave = 8 queries x 8 lanes; lane owns x-slot j>>2, ch-group j&3.
// __launch_bounds__(256,4): VGPR cap 128 (was 32) -> 2-deep software-pipelined
// gather, 16 dwordx4 loads in flight; L2 latency hidden under MACs.
__global__ __launch_bounds__(256, 4) void deform_head(
    const bf16* __restrict__ vproj, const float* __restrict__ offaw,
    const float* __restrict__ refp, bf16* __restrict__ sampled)
{
    const int gid = blockIdx.x;
    const int idx8 = gid & 7;                 // -> XCD (round-robin heuristic)
    const int mid = gid >> 3;
    const int qg = mid % (NQ / 32);
    const int hsel = mid / (NQ / 32);         // 0 or 1 (grid-half)
    const int h = (idx8 >> 1) + (hsel << 2);
    const int b = idx8 & 1;

    const int wv = threadIdx.x >> 6;
    const int t = threadIdx.x & 63;
    const int qq = t >> 3, e = t & 7;
    const int wq = wv * 8 + qq;               // 0..31
    const int q = qg * 32 + wq;
    const int bq = b * NQ + q;

    __shared__ int   s_idx[32][17];           // byte offset of pair row
    __shared__ __align__(16) float s_w[32][17][4];  // [y0x0, y1x0, y0x1, y1x1]

    const float* row = offaw + (size_t)bq * 384;

    // ---- softmax over 16 logits: 8 lanes x 2, butterflies strides 1,2,4
    float l0 = row[256 + h * 16 + e];
    float l1 = row[256 + h * 16 + e + 8];
    float m = fmaxf(l0, l1);
    m = fmaxf(m, __shfl_xor(m, 1));
    m = fmaxf(m, __shfl_xor(m, 2));
    m = fmaxf(m, __shfl_xor(m, 4));
    float e0 = __expf(l0 - m), e1 = __expf(l1 - m);
    float ssum = e0 + e1;
    ssum += __shfl_xor(ssum, 1);
    ssum += __shfl_xor(ssum, 2);
    ssum += __shfl_xor(ssum, 4);
    float rs = 1.0f / ssum;
    float awv[2] = {e0 * rs, e1 * rs};

    // ---- precompute 2 samples per lane (lp = e, e+8), border-exact slot weights
    #pragma unroll
    for (int sI = 0; sI < 2; sI++) {
        int lp = e + sI * 8;
        int l = lp >> 2;
        int Wl = 128 >> l, Hl = Wl;
        int st = (l == 0) ? 0 : (l == 1) ? 16384 : (l == 2) ? 20480 : 21504;
        float2 rp = *(const float2*)&refp[((size_t)bq * 4 + l) * 2];
        float2 oxy = *(const float2*)&row[h * 32 + lp * 2];
        float fW = (float)Wl, fH = (float)Hl;
        float x = (rp.x + oxy.x / fW) * fW - 0.5f;
        float y = (rp.y + oxy.y / fH) * fH - 0.5f;
        float xf = floorf(x), yf = floorf(y);
        int x0 = (int)xf, y0 = (int)yf;
        float wx1 = x - xf, wx0 = 1.f - wx1;
        float wy1 = y - yf, wy0 = 1.f - wy1;
        float aw = awv[sI];
        float wx0p = ((x0 >= 0) && (x0 < Wl)) ? wx0 : 0.f;
        float wx1p = ((x0 + 1 >= 0) && (x0 + 1 < Wl)) ? wx1 : 0.f;
        float wy0p = ((y0 >= 0) && (y0 < Hl)) ? wy0 : 0.f;
        float wy1p = ((y0 + 1 >= 0) && (y0 + 1 < Hl)) ? wy1 : 0.f;
        int px = min(max(x0, 0), Wl - 2), py = min(max(y0, 0), Hl - 2);
        int cx0 = min(max(x0, 0), Wl - 1), cx1 = min(max(x0 + 1, 0), Wl - 1);
        int cy0 = min(max(y0, 0), Hl - 1), cy1 = min(max(y0 + 1, 0), Hl - 1);
        float sx0 = ((cx0 == px) ? wx0p : 0.f) + ((cx1 == px) ? wx1p : 0.f);
        float sx1 = ((cx0 == px + 1) ? wx0p : 0.f) + ((cx1 == px + 1) ? wx1p : 0.f);
        float sy0 = ((cy0 == py) ? wy0p : 0.f) + ((cy1 == py) ? wy1p : 0.f);
        float sy1 = ((cy0 == py + 1) ? wy0p : 0.f) + ((cy1 == py + 1) ? wy1p : 0.f);
        s_idx[wq][lp] = (st + py * Wl + px) * 64;   // byte offset ( *32ch *2B )
        s_w[wq][lp][0] = sy0 * sx0 * aw;            // y0, x0
        s_w[wq][lp][1] = sy1 * sx0 * aw;            // y1, x0
        s_w[wq][lp][2] = sy0 * sx1 * aw;            // y0, x1
        s_w[wq][lp][3] = sy1 * sx1 * aw;            // y1, x1
    }
    // wave-local LDS RAW (each wave reads only its own 8 wq rows) -> lgkmcnt only

    // ---- gather: lane (qq, j): xslot = j>>2, chgrp = j&3
    const int j = t & 7;
    const int xslot = j >> 2;
    const int chgrp = j & 3;
    const char* vb = (const char*)vproj + (size_t)(b * NH + h) * V_LEN * 64;
    const int voffbase = j * 16;   // xslot*64 + chgrp*16 within the 128B pair

    // preload all 16 per-sample byte offsets to registers
    int offv[16];
    #pragma unroll
    for (int i = 0; i < 16; i++) offv[i] = s_idx[wq][i] + voffbase;

    f32x2 a01 = {0.f, 0.f}, a23 = {0.f, 0.f}, a45 = {0.f, 0.f}, a67 = {0.f, 0.f};

    uint4 rA[8], rB[8];
    auto mac_group = [&](const uint4* r, int G) {
        #pragma unroll
        for (int k = 0; k < 4; k++) {
            const int i = G * 4 + k;
            f32x2 wp = *(const f32x2*)&s_w[wq][i][xslot * 2];
            acc8(r[k * 2 + 0], wp[0], a01, a23, a45, a67);
            acc8(r[k * 2 + 1], wp[1], a01, a23, a45, a67);
        }
    };

    // 2-deep pipeline: two groups (16 loads) in flight
    load_group<0>(vb, offv, rA);
    load_group<1>(vb, offv, rB);
    mac_group(rA, 0);
    load_group<2>(vb, offv, rA);
    mac_group(rB, 1);
    load_group<3>(vb, offv, rB);
    mac_group(rA, 2);
    mac_group(rB, 3);

    // combine x-slots (lanes j and j^4 hold same channels)
    float sarr[8] = {a01[0], a01[1], a23[0], a23[1], a45[0], a45[1], a67[0], a67[1]};
    #pragma unroll
    for (int i = 0; i < 8; i++) sarr[i] += __shfl_xor(sarr[i], 4);

    if ((t & 4) == 0) {                           // one lane per (query, chgrp)
        bf16x8 o;
        #pragma unroll
        for (int i = 0; i < 8; i++) o[i] = (bf16)sarr[i];
        *(bf16x8*)&sampled[(size_t)bq * 256 + h * 32 + chgrp * 8] = o;
    }
}

extern "C" void kernel_launch(void* const* d_in, const int* in_sizes, int n_in,
                              void* d_out, int out_size, void* d_ws, size_t ws_size,
                              hipStream_t stream)
{
    const float* query  = (const float*)d_in[0];
    const float* refp   = (const float*)d_in[1];
    const float* value  = (const float*)d_in[2];
    const float* W_off  = (const float*)d_in[3];
    const float* b_off  = (const float*)d_in[4];
    const float* W_attn = (const float*)d_in[5];
    const float* b_attn = (const float*)d_in[6];
    const float* W_v    = (const float*)d_in[7];
    const float* b_v    = (const float*)d_in[8];
    const float* W_out  = (const float*)d_in[9];
    const float* b_out  = (const float*)d_in[10];
    float* out = (float*)d_out;

    const int M = BS * NQ;  // 43520

    char* ws = (char*)d_ws;
    bf16*  WTv   = (bf16*)ws;                      ws += 256 * 256 * 2;
    bf16*  WToa  = (bf16*)ws;                      ws += 384 * 256 * 2;
    bf16*  WTu   = (bf16*)ws;                      ws += 256 * 256 * 2;
    float* bcat  = (float*)ws;                     ws += 384 * 4;
    bf16*  vproj = (bf16*)ws;                      ws += (size_t)M * 256 * 2;   // per-head layout
    float* offaw = (float*)ws;                     ws += (size_t)M * 384 * 4;
    bf16*  samp  = (bf16*)ws;                      ws += (size_t)M * 256 * 2;

    cast_all<<<57, 256, 0, stream>>>(W_v, W_off, W_attn, W_out, b_off, b_attn,
                                     WTv, WToa, WTu, bcat);

    // vproj = bf16(value @ W_v + b_v), per-head layout [b][h][v][32]
    gemm_mfma<true, 2><<<(M / 128) * 2, 256, 0, stream>>>(value, WTv, b_v, vproj, 256, 256, 2);
    // offaw = query @ [W_off | W_attn] + [b_off | b_attn]   (fp32 out)
    gemm_mfma<true, 0><<<(M / 128) * 3, 256, 0, stream>>>(query, WToa, bcat, offaw, 384, 256, 3);
    // softmax + deformable sampling -> bf16, per-(b,h) XCD-resident blocks
    deform_head<<<2 * NH * (NQ / 32), 256, 0, stream>>>(vproj, offaw, refp, samp);
    // out = sampled @ W_out + b_out  (fp32 out)
    gemm_mfma<false, 0><<<(M / 128) * 2, 256, 0, stream>>>(samp, WTu, b_out, out, 256, 256, 2);
}